// Round 1
// baseline (576.316 us; speedup 1.0000x reference)
//
#include <hip/hip_runtime.h>
#include <hip/hip_bf16.h>

// ---------------- types ----------------
typedef __attribute__((ext_vector_type(8))) _Float16 f16x8;
typedef __attribute__((ext_vector_type(4))) float  f32x4;

#define H_DIM 1152
#define H_VEC (H_DIM / 4)   // 288 float4 per token

__device__ __forceinline__ float nvfp4_level(float xn) {
    // nearest NVFP4 level, ties to lower == fp32 argmin over |xn - level|
    return xn <= 0.25f ? 0.0f
         : xn <= 0.75f ? 0.5f
         : xn <= 1.25f ? 1.0f
         : xn <= 1.75f ? 1.5f
         : xn <= 2.5f  ? 2.0f
         : xn <= 3.5f  ? 3.0f
         : xn <= 5.0f  ? 4.0f : 6.0f;
}

// ---------------- kernel 1: smooth + prescale + NVFP4 fake quant -> fp16 ----------------
// one wave (64 lanes) per token; 4 tokens per 256-thread block (packing for
// better per-CU wave residency vs 1-wave workgroups). Math identical to prior version.
__global__ __launch_bounds__(256) void quant_kernel(
    const float4* __restrict__ x4, const float4* __restrict__ s4,
    _Float16* __restrict__ xq)
{
    const int t    = (blockIdx.x << 2) + (threadIdx.x >> 6);
    const int lane = threadIdx.x & 63;
    const float4* xrow = x4 + (size_t)t * H_VEC;

    float4 v[5];
    int    fidx[5];
    float  m = 0.f;
    #pragma unroll
    for (int i = 0; i < 5; ++i) {
        const int f = (i < 4) ? (lane + 64 * i) : (256 + (lane & 31));
        fidx[i] = f;
        const float4 xx = xrow[f];
        const float4 ss = s4[f];
        float4 vv;
        vv.x = xx.x * ss.x; vv.y = xx.y * ss.y;
        vv.z = xx.z * ss.z; vv.w = xx.w * ss.w;
        v[i] = vv;
        m = fmaxf(m, fmaxf(fmaxf(fabsf(vv.x), fabsf(vv.y)),
                           fmaxf(fabsf(vv.z), fabsf(vv.w))));
    }
    // token max (upper lanes' tail slot duplicates lower lanes' -> max unchanged)
    #pragma unroll
    for (int off = 32; off; off >>= 1)
        m = fmaxf(m, __shfl_xor(m, off, 64));
    const float pre_scale = fmaxf(m, 1e-12f) / 6.0f;

    #pragma unroll
    for (int i = 0; i < 5; ++i) {
        float4 p;
        p.x = v[i].x / pre_scale;
        p.y = v[i].y / pre_scale;
        p.z = v[i].z / pre_scale;
        p.w = v[i].w / pre_scale;
        float g = fmaxf(fmaxf(fabsf(p.x), fabsf(p.y)),
                        fmaxf(fabsf(p.z), fabsf(p.w)));
        // 16-block amax over 4 consecutive lanes
        g = fmaxf(g, __shfl_xor(g, 1, 64));
        g = fmaxf(g, __shfl_xor(g, 2, 64));
        const float scale = fmaxf(g, 1e-12f) / 6.0f;

        alignas(8) _Float16 o[4];
        {
            float q;
            q = copysignf(nvfp4_level(fabsf(p.x) / scale) * scale, p.x) * pre_scale;
            o[0] = (_Float16)q;
            q = copysignf(nvfp4_level(fabsf(p.y) / scale) * scale, p.y) * pre_scale;
            o[1] = (_Float16)q;
            q = copysignf(nvfp4_level(fabsf(p.z) / scale) * scale, p.z) * pre_scale;
            o[2] = (_Float16)q;
            q = copysignf(nvfp4_level(fabsf(p.w) / scale) * scale, p.w) * pre_scale;
            o[3] = (_Float16)q;
        }
        if (i < 4 || lane < 32) {
            _Float16* dst = xq + (size_t)t * H_DIM + fidx[i] * 4;
            *(uint2*)dst = *(const uint2*)o;
        }
    }
}

// ---------------- kernel 2: w fp32 -> fp16 ----------------
__global__ __launch_bounds__(256) void wconv_kernel(
    const float* __restrict__ w, _Float16* __restrict__ wq, int n)
{
    int i = (blockIdx.x * 256 + threadIdx.x) * 4;
    if (i < n) {
        float4 v = *(const float4*)(w + i);
        alignas(8) _Float16 o[4];
        o[0] = (_Float16)v.x;
        o[1] = (_Float16)v.y;
        o[2] = (_Float16)v.z;
        o[3] = (_Float16)v.w;
        *(uint2*)(wq + i) = *(const uint2*)o;
    }
}

// ---------------- async global->LDS 16B helper ----------------
__device__ __forceinline__ void async_copy16(const void* gptr, void* lptr)
{
    __builtin_amdgcn_global_load_lds(
        (const __attribute__((address_space(1))) unsigned int*)gptr,
        (__attribute__((address_space(3))) unsigned int*)lptr,
        16, 0, 0);
}

// compiler-level memory fence + HW barrier (no implicit vmcnt drain — that is the point)
#define BARRIER() do { asm volatile("" ::: "memory"); \
                       __builtin_amdgcn_s_barrier();  \
                       asm volatile("" ::: "memory"); } while (0)

// ---------------- kernel 3: fp16 GEMM, C[t,o] = sum_k A[t,k]*B[o,k] + bias[o] ----
// 256x256 tile, BK=64, 512 threads (8 waves as 2Mx4N, each owning a 128x64 sub-tile).
// 4-phase schedule per K-tile, raw barriers, counted vmcnt(8) at tile boundary only
// (prefetch distance 2 K-tiles stays in flight across barriers). LDS reads XOR-
// swizzled ((row&7)<<4 on the byte offset) with the inverse swizzle applied to the
// per-lane global_load_lds SOURCE address (LDS dest stays linear).
#define BM 256
#define BN 256
#define BK 64

__global__ __launch_bounds__(512, 2) void gemm_bt_kernel(
    const _Float16* __restrict__ A,  // [M,K]
    const _Float16* __restrict__ B,  // [N,K]
    const float* __restrict__ bias,  // [N]
    float* __restrict__ C,           // [M,N]
    int M, int N, int K)
{
    __shared__ alignas(16) _Float16 sA[2][BM * BK];   // 64 KiB
    __shared__ alignas(16) _Float16 sB[2][BN * BK];   // 64 KiB

    const int tid    = threadIdx.x;
    const int wave   = tid >> 6;
    const int lane   = tid & 63;
    const int lane16 = lane & 15;
    const int quad   = lane >> 4;

    // XCD-aware block swizzle (nwg = 18*64 = 1152, divisible by 8 -> bijective)
    const int nbx = gridDim.x;
    const int nwg = nbx * gridDim.y;
    int bid = blockIdx.y * nbx + blockIdx.x;
    if ((nwg & 7) == 0) {
        const int cpx = nwg >> 3;
        bid = (bid & 7) * cpx + (bid >> 3);
    }
    const int m0 = (bid / nbx) * BM;
    const int n0 = (bid % nbx) * BN;

    const int wr = wave >> 2;   // 0..1 : which 128-row half of the M-tile
    const int wc = wave & 3;    // 0..3 : which 64-col slice of the N-tile

    const int NT = K / BK;

    // staging geometry: tile = 256 rows x 64 fp16 = 2048 16B-chunks; 512 thr x 4 loads.
    // chunk c -> row = c>>3, 16B-slot = c&7. LDS dest is linear (HW: base + lane*16);
    // the read-side XOR swizzle is pre-applied to the global source slot instead.
    int srcA[4], srcB[4], ldst[4];
    #pragma unroll
    for (int s = 0; s < 4; ++s) {
        const int base = (wave * 4 + s) * 64;            // wave-uniform chunk base
        const int c    = base + lane;
        const int r    = c >> 3;                          // row within tile, 0..255
        const int sw   = ((c & 7) * 8) ^ ((r & 7) << 3);  // element offset in row (16B units swizzled)
        srcA[s] = (m0 + r) * K + sw;
        srcB[s] = (n0 + r) * K + sw;
        ldst[s] = base * 16;                              // LDS byte offset
    }

    auto stage = [&](int t, int d) {
        const int k0 = t * BK;
        #pragma unroll
        for (int s = 0; s < 4; ++s) {
            async_copy16(A + srcA[s] + k0, (char*)(&sA[d][0]) + ldst[s]);
            async_copy16(B + srcB[s] + k0, (char*)(&sB[d][0]) + ldst[s]);
        }
    };

    // prologue: tiles 0 and 1 in flight; wait tile0 (its 8 loads are the oldest)
    stage(0, 0);
    if (NT > 1) stage(1, 1);
    asm volatile("s_waitcnt vmcnt(8)" ::: "memory");
    BARRIER();

    f32x4 acc[8][4] = {};
    f16x8 b[4][2];

    for (int t = 0; t < NT; ++t) {
        const int d = t & 1;
        const _Float16* tA = &sA[d][0];
        const _Float16* tB = &sB[d][0];

        #pragma unroll
        for (int p = 0; p < 4; ++p) {
            // ds-load this phase's A quadrant (4 x ds_read_b128), swizzled
            f16x8 a[2][2];
            #pragma unroll
            for (int ii = 0; ii < 2; ++ii) {
                const int r = wr * 128 + (p * 2 + ii) * 16 + lane16;
                #pragma unroll
                for (int ks = 0; ks < 2; ++ks)
                    a[ii][ks] = *(const f16x8*)(tA + r * 64 +
                                 ((ks * 32 + quad * 8) ^ ((r & 7) << 3)));
            }
            if (p == 0) {
                // whole-tile B fragments once per K-tile (8 x ds_read_b128), kept in regs
                #pragma unroll
                for (int j = 0; j < 4; ++j) {
                    const int rb = wc * 64 + j * 16 + lane16;
                    #pragma unroll
                    for (int ks = 0; ks < 2; ++ks)
                        b[j][ks] = *(const f16x8*)(tB + rb * 64 +
                                    ((ks * 32 + quad * 8) ^ ((rb & 7) << 3)));
                }
            }
            BARRIER();                                         // phase-align waves
            asm volatile("s_waitcnt lgkmcnt(0)" ::: "memory"); // own ds_reads landed
            __builtin_amdgcn_s_setprio(1);
            #pragma unroll
            for (int ii = 0; ii < 2; ++ii)
                #pragma unroll
                for (int j = 0; j < 4; ++j)
                    #pragma unroll
                    for (int ks = 0; ks < 2; ++ks)
                        acc[p * 2 + ii][j] = __builtin_amdgcn_mfma_f32_16x16x32_f16(
                            a[ii][ks], b[j][ks], acc[p * 2 + ii][j], 0, 0, 0);
            __builtin_amdgcn_s_setprio(0);
            BARRIER();                                         // phase done (all reads of
                                                               // this quadrant complete)
        }

        // tile boundary: all waves are past ALL ds_reads of buffer d (final phase
        // barrier above), so it is safe to issue t+2's staging into d. Then the
        // counted vmcnt(8) drains exactly tile t+1's 8 loads (oldest), leaving
        // t+2's 8 in flight across the barrier.
        if (t + 2 < NT) {
            stage(t + 2, d);
            asm volatile("s_waitcnt vmcnt(8)" ::: "memory");
        } else {
            asm volatile("s_waitcnt vmcnt(0)" ::: "memory");
        }
        BARRIER();
    }

    // epilogue: C/D layout col = lane16, row = quad*4 + reg
    #pragma unroll
    for (int i = 0; i < 8; ++i) {
        const int m = m0 + wr * 128 + i * 16 + quad * 4;
        #pragma unroll
        for (int j = 0; j < 4; ++j) {
            const int n = n0 + wc * 64 + j * 16 + lane16;
            const float bv = bias[n];
            float* cp = C + (size_t)m * N + n;
            #pragma unroll
            for (int r2 = 0; r2 < 4; ++r2)
                cp[(size_t)r2 * N] = acc[i][j][r2] + bv;
        }
    }
}

// ---------------- launch ----------------
extern "C" void kernel_launch(void* const* d_in, const int* in_sizes, int n_in,
                              void* d_out, int out_size, void* d_ws, size_t ws_size,
                              hipStream_t stream)
{
    const float* x      = (const float*)d_in[0];
    const float* w      = (const float*)d_in[1];
    const float* smooth = (const float*)d_in[2];
    const float* bias   = (const float*)d_in[3];
    float* out = (float*)d_out;

    const int H = in_sizes[2];            // 1152
    const int T = in_sizes[0] / H;        // 16384
    const int O = in_sizes[3];            // 4608

    _Float16* xq = (_Float16*)d_ws;
    _Float16* wq = (_Float16*)((char*)d_ws + (size_t)T * H * sizeof(_Float16));

    quant_kernel<<<T / 4, 256, 0, stream>>>((const float4*)x, (const float4*)smooth, xq);
    wconv_kernel<<<(O * H / 4 + 255) / 256, 256, 0, stream>>>(w, wq, O * H);

    dim3 grid(O / BN, T / BM);
    gemm_bt_kernel<<<grid, 512, 0, stream>>>(xq, wq, bias, out, T, O, H);
}

// Round 2
// 556.919 us; speedup vs baseline: 1.0348x; 1.0348x over previous
//
#include <hip/hip_runtime.h>
#include <hip/hip_bf16.h>

// ---------------- types ----------------
typedef __attribute__((ext_vector_type(8))) _Float16 f16x8;
typedef __attribute__((ext_vector_type(4))) float  f32x4;

#define H_DIM 1152
#define H_VEC (H_DIM / 4)   // 288 float4 per token

__device__ __forceinline__ float nvfp4_level(float xn) {
    // nearest NVFP4 level, ties to lower == fp32 argmin over |xn - level|
    return xn <= 0.25f ? 0.0f
         : xn <= 0.75f ? 0.5f
         : xn <= 1.25f ? 1.0f
         : xn <= 1.75f ? 1.5f
         : xn <= 2.5f  ? 2.0f
         : xn <= 3.5f  ? 3.0f
         : xn <= 5.0f  ? 4.0f : 6.0f;
}

// ---------------- kernel 1: smooth + prescale + NVFP4 fake quant -> fp16 ----------------
// one wave (64 lanes) per token; 4 tokens per 256-thread block. Math identical.
__global__ __launch_bounds__(256) void quant_kernel(
    const float4* __restrict__ x4, const float4* __restrict__ s4,
    _Float16* __restrict__ xq)
{
    const int t    = (blockIdx.x << 2) + (threadIdx.x >> 6);
    const int lane = threadIdx.x & 63;
    const float4* xrow = x4 + (size_t)t * H_VEC;

    float4 v[5];
    int    fidx[5];
    float  m = 0.f;
    #pragma unroll
    for (int i = 0; i < 5; ++i) {
        const int f = (i < 4) ? (lane + 64 * i) : (256 + (lane & 31));
        fidx[i] = f;
        const float4 xx = xrow[f];
        const float4 ss = s4[f];
        float4 vv;
        vv.x = xx.x * ss.x; vv.y = xx.y * ss.y;
        vv.z = xx.z * ss.z; vv.w = xx.w * ss.w;
        v[i] = vv;
        m = fmaxf(m, fmaxf(fmaxf(fabsf(vv.x), fabsf(vv.y)),
                           fmaxf(fabsf(vv.z), fabsf(vv.w))));
    }
    #pragma unroll
    for (int off = 32; off; off >>= 1)
        m = fmaxf(m, __shfl_xor(m, off, 64));
    const float pre_scale = fmaxf(m, 1e-12f) / 6.0f;

    #pragma unroll
    for (int i = 0; i < 5; ++i) {
        float4 p;
        p.x = v[i].x / pre_scale;
        p.y = v[i].y / pre_scale;
        p.z = v[i].z / pre_scale;
        p.w = v[i].w / pre_scale;
        float g = fmaxf(fmaxf(fabsf(p.x), fabsf(p.y)),
                        fmaxf(fabsf(p.z), fabsf(p.w)));
        g = fmaxf(g, __shfl_xor(g, 1, 64));
        g = fmaxf(g, __shfl_xor(g, 2, 64));
        const float scale = fmaxf(g, 1e-12f) / 6.0f;

        alignas(8) _Float16 o[4];
        {
            float q;
            q = copysignf(nvfp4_level(fabsf(p.x) / scale) * scale, p.x) * pre_scale;
            o[0] = (_Float16)q;
            q = copysignf(nvfp4_level(fabsf(p.y) / scale) * scale, p.y) * pre_scale;
            o[1] = (_Float16)q;
            q = copysignf(nvfp4_level(fabsf(p.z) / scale) * scale, p.z) * pre_scale;
            o[2] = (_Float16)q;
            q = copysignf(nvfp4_level(fabsf(p.w) / scale) * scale, p.w) * pre_scale;
            o[3] = (_Float16)q;
        }
        if (i < 4 || lane < 32) {
            _Float16* dst = xq + (size_t)t * H_DIM + fidx[i] * 4;
            *(uint2*)dst = *(const uint2*)o;
        }
    }
}

// ---------------- kernel 2: w fp32 -> fp16 ----------------
__global__ __launch_bounds__(256) void wconv_kernel(
    const float* __restrict__ w, _Float16* __restrict__ wq, int n)
{
    int i = (blockIdx.x * 256 + threadIdx.x) * 4;
    if (i < n) {
        float4 v = *(const float4*)(w + i);
        alignas(8) _Float16 o[4];
        o[0] = (_Float16)v.x;
        o[1] = (_Float16)v.y;
        o[2] = (_Float16)v.z;
        o[3] = (_Float16)v.w;
        *(uint2*)(wq + i) = *(const uint2*)o;
    }
}

// ---------------- async global->LDS 16B helper ----------------
__device__ __forceinline__ void async_copy16(const void* gptr, void* lptr)
{
    __builtin_amdgcn_global_load_lds(
        (const __attribute__((address_space(1))) unsigned int*)gptr,
        (__attribute__((address_space(3))) unsigned int*)lptr,
        16, 0, 0);
}

// ---------------- kernel 3: fp16 GEMM, C[t,o] = sum_k A[t,k]*B[o,k] + bias[o] ----
// 256x256 tile, BK=64, 512 threads (8 waves, 2Mx4N). Pipelined 4-phase schedule:
// phase p issues phase p+1's A ds_reads (compiler emits counted lgkmcnt), ONE
// alignment barrier per phase, setprio(1) around the 16-MFMA cluster -> LDS reads
// overlap the matrix pipe. Counted vmcnt(8) at tile boundary only (2 K-tiles of
// staging in flight across barriers). Swizzle: linear LDS dest, inverse-swizzled
// global_load_lds source, XOR-swizzled ds_read addresses (both-sides pattern).
#define BM 256
#define BN 256
#define BK 64

__global__ __launch_bounds__(512, 2) void gemm_bt_kernel(
    const _Float16* __restrict__ A,  // [M,K]
    const _Float16* __restrict__ B,  // [N,K]
    const float* __restrict__ bias,  // [N]
    float* __restrict__ C,           // [M,N]
    int M, int N, int K)
{
    __shared__ alignas(16) _Float16 sA[2][BM * BK];   // 64 KiB
    __shared__ alignas(16) _Float16 sB[2][BN * BK];   // 64 KiB

    const int tid    = threadIdx.x;
    const int wave   = tid >> 6;
    const int lane   = tid & 63;
    const int lane16 = lane & 15;
    const int quad   = lane >> 4;

    // XCD-aware block swizzle (nwg = 18*64 = 1152, divisible by 8 -> bijective)
    const int nbx = gridDim.x;
    const int nwg = nbx * gridDim.y;
    int bid = blockIdx.y * nbx + blockIdx.x;
    if ((nwg & 7) == 0) {
        const int cpx = nwg >> 3;
        bid = (bid & 7) * cpx + (bid >> 3);
    }
    const int m0 = (bid / nbx) * BM;
    const int n0 = (bid % nbx) * BN;

    const int wr = wave >> 2;   // 0..1 : 128-row half of M-tile
    const int wc = wave & 3;    // 0..3 : 64-col slice of N-tile
    const int NT = K / BK;

    // staging geometry: tile = 256 rows x 64 fp16 = 2048 16B-chunks; 512 thr x 4.
    // LDS dest linear (HW: base + lane*16); read-side XOR pre-applied to the
    // global source slot.
    int srcA[4], srcB[4], ldst[4];
    #pragma unroll
    for (int s = 0; s < 4; ++s) {
        const int base = (wave * 4 + s) * 64;            // wave-uniform chunk base
        const int c    = base + lane;
        const int r    = c >> 3;                          // row within tile
        const int sw   = ((c & 7) * 8) ^ ((r & 7) << 3);  // swizzled 8-elem slot
        srcA[s] = (m0 + r) * K + sw;
        srcB[s] = (n0 + r) * K + sw;
        ldst[s] = base * 16;                              // LDS byte offset
    }

    auto stage = [&](int t, int d) {
        const int k0 = t * BK;
        #pragma unroll
        for (int s = 0; s < 4; ++s) {
            async_copy16(A + srcA[s] + k0, (char*)(&sA[d][0]) + ldst[s]);
            async_copy16(B + srcB[s] + k0, (char*)(&sB[d][0]) + ldst[s]);
        }
    };

    // ds_read XOR term: row&7 == lane16&7 for every fragment row -> per-thread const
    const int xr = (lane16 & 7) << 3;

    // prologue: tiles 0,1 in flight; tile 0 complete before first reads
    stage(0, 0);
    if (NT > 1) stage(1, 1);
    asm volatile("s_waitcnt vmcnt(8)" ::: "memory");
    __builtin_amdgcn_s_barrier();
    asm volatile("" ::: "memory");   // pin first-tile ds_reads below the barrier

    f32x4 acc[8][4] = {};

    for (int t = 0; t < NT; ++t) {
        const int d = t & 1;
        const _Float16* tA = &sA[d][0];
        const _Float16* tB = &sB[d][0];

        f16x8 b[4][2];
        f16x8 a[2][2][2];   // [phase parity][ii][ks] — all indices compile-time

        // phase -1: whole-tile B (8 x ds_read_b128) + phase-0 A (4 x ds_read_b128)
        #pragma unroll
        for (int j = 0; j < 4; ++j) {
            const int rb = wc * 64 + j * 16 + lane16;
            #pragma unroll
            for (int ks = 0; ks < 2; ++ks)
                b[j][ks] = *(const f16x8*)(tB + rb * 64 + ((ks * 32 + quad * 8) ^ xr));
        }
        #pragma unroll
        for (int ii = 0; ii < 2; ++ii) {
            const int r = wr * 128 + ii * 16 + lane16;
            #pragma unroll
            for (int ks = 0; ks < 2; ++ks)
                a[0][ii][ks] = *(const f16x8*)(tA + r * 64 + ((ks * 32 + quad * 8) ^ xr));
        }

        #pragma unroll
        for (int p = 0; p < 4; ++p) {
            if (p < 3) {
                // issue NEXT phase's A reads — stay in flight under this phase's MFMAs
                #pragma unroll
                for (int ii = 0; ii < 2; ++ii) {
                    const int r = wr * 128 + ((p + 1) * 2 + ii) * 16 + lane16;
                    #pragma unroll
                    for (int ks = 0; ks < 2; ++ks)
                        a[(p + 1) & 1][ii][ks] =
                            *(const f16x8*)(tA + r * 64 + ((ks * 32 + quad * 8) ^ xr));
                }
            } else {
                // last phase: drain ALL own LDS reads of buffer d before the barrier,
                // so staging into d (below) cannot race any wave's reads.
                asm volatile("s_waitcnt lgkmcnt(0)" ::: "memory");
            }
            __builtin_amdgcn_s_barrier();   // phase-align waves before MFMA burst
            if (p == 3) {
                asm volatile("" ::: "memory");          // pin stage below barrier
                if (t + 2 < NT) stage(t + 2, d);        // buffer d fully retired
            }
            __builtin_amdgcn_s_setprio(1);
            #pragma unroll
            for (int ii = 0; ii < 2; ++ii)
                #pragma unroll
                for (int j = 0; j < 4; ++j)
                    #pragma unroll
                    for (int ks = 0; ks < 2; ++ks)
                        acc[p * 2 + ii][j] = __builtin_amdgcn_mfma_f32_16x16x32_f16(
                            a[p & 1][ii][ks], b[j][ks], acc[p * 2 + ii][j], 0, 0, 0);
            __builtin_amdgcn_s_setprio(0);
        }

        // tile boundary: wait tile t+1's 8 loads (oldest) complete; t+2's 8 stay
        // in flight across the barrier. Barrier publishes all waves' staging.
        if (t + 2 < NT) asm volatile("s_waitcnt vmcnt(8)" ::: "memory");
        else            asm volatile("s_waitcnt vmcnt(0)" ::: "memory");
        __builtin_amdgcn_s_barrier();
        asm volatile("" ::: "memory");   // pin next tile's ds_reads below barrier
    }

    // epilogue: C/D layout col = lane16, row = quad*4 + reg
    #pragma unroll
    for (int i = 0; i < 8; ++i) {
        const int m = m0 + wr * 128 + i * 16 + quad * 4;
        #pragma unroll
        for (int j = 0; j < 4; ++j) {
            const int n = n0 + wc * 64 + j * 16 + lane16;
            const float bv = bias[n];
            float* cp = C + (size_t)m * N + n;
            #pragma unroll
            for (int r2 = 0; r2 < 4; ++r2)
                cp[(size_t)r2 * N] = acc[i][j][r2] + bv;
        }
    }
}

// ---------------- launch ----------------
extern "C" void kernel_launch(void* const* d_in, const int* in_sizes, int n_in,
                              void* d_out, int out_size, void* d_ws, size_t ws_size,
                              hipStream_t stream)
{
    const float* x      = (const float*)d_in[0];
    const float* w      = (const float*)d_in[1];
    const float* smooth = (const float*)d_in[2];
    const float* bias   = (const float*)d_in[3];
    float* out = (float*)d_out;

    const int H = in_sizes[2];            // 1152
    const int T = in_sizes[0] / H;        // 16384
    const int O = in_sizes[3];            // 4608

    _Float16* xq = (_Float16*)d_ws;
    _Float16* wq = (_Float16*)((char*)d_ws + (size_t)T * H * sizeof(_Float16));

    quant_kernel<<<T / 4, 256, 0, stream>>>((const float4*)x, (const float4*)smooth, xq);
    wconv_kernel<<<(O * H / 4 + 255) / 256, 256, 0, stream>>>(w, wq, O * H);

    dim3 grid(O / BN, T / BM);
    gemm_bt_kernel<<<grid, 512, 0, stream>>>(xq, wq, bias, out, T, O, H);
}

// Round 3
// 547.729 us; speedup vs baseline: 1.0522x; 1.0168x over previous
//
#include <hip/hip_runtime.h>
#include <hip/hip_bf16.h>

// ---------------- types ----------------
typedef __attribute__((ext_vector_type(8))) _Float16 f16x8;
typedef __attribute__((ext_vector_type(4))) float  f32x4;

#define H_DIM 1152
#define H_VEC (H_DIM / 4)   // 288 float4 per token

__device__ __forceinline__ float nvfp4_level(float xn) {
    // nearest NVFP4 level, ties to lower == fp32 argmin over |xn - level|
    return xn <= 0.25f ? 0.0f
         : xn <= 0.75f ? 0.5f
         : xn <= 1.25f ? 1.0f
         : xn <= 1.75f ? 1.5f
         : xn <= 2.5f  ? 2.0f
         : xn <= 3.5f  ? 3.0f
         : xn <= 5.0f  ? 4.0f : 6.0f;
}

// ---------------- kernel 1: smooth + prescale + NVFP4 fake quant -> fp16 ----------------
// one wave (64 lanes) per token; 4 tokens per 256-thread block. Math identical.
__global__ __launch_bounds__(256) void quant_kernel(
    const float4* __restrict__ x4, const float4* __restrict__ s4,
    _Float16* __restrict__ xq)
{
    const int t    = (blockIdx.x << 2) + (threadIdx.x >> 6);
    const int lane = threadIdx.x & 63;
    const float4* xrow = x4 + (size_t)t * H_VEC;

    float4 v[5];
    int    fidx[5];
    float  m = 0.f;
    #pragma unroll
    for (int i = 0; i < 5; ++i) {
        const int f = (i < 4) ? (lane + 64 * i) : (256 + (lane & 31));
        fidx[i] = f;
        const float4 xx = xrow[f];
        const float4 ss = s4[f];
        float4 vv;
        vv.x = xx.x * ss.x; vv.y = xx.y * ss.y;
        vv.z = xx.z * ss.z; vv.w = xx.w * ss.w;
        v[i] = vv;
        m = fmaxf(m, fmaxf(fmaxf(fabsf(vv.x), fabsf(vv.y)),
                           fmaxf(fabsf(vv.z), fabsf(vv.w))));
    }
    #pragma unroll
    for (int off = 32; off; off >>= 1)
        m = fmaxf(m, __shfl_xor(m, off, 64));
    const float pre_scale = fmaxf(m, 1e-12f) / 6.0f;

    #pragma unroll
    for (int i = 0; i < 5; ++i) {
        float4 p;
        p.x = v[i].x / pre_scale;
        p.y = v[i].y / pre_scale;
        p.z = v[i].z / pre_scale;
        p.w = v[i].w / pre_scale;
        float g = fmaxf(fmaxf(fabsf(p.x), fabsf(p.y)),
                        fmaxf(fabsf(p.z), fabsf(p.w)));
        g = fmaxf(g, __shfl_xor(g, 1, 64));
        g = fmaxf(g, __shfl_xor(g, 2, 64));
        const float scale = fmaxf(g, 1e-12f) / 6.0f;

        alignas(8) _Float16 o[4];
        {
            float q;
            q = copysignf(nvfp4_level(fabsf(p.x) / scale) * scale, p.x) * pre_scale;
            o[0] = (_Float16)q;
            q = copysignf(nvfp4_level(fabsf(p.y) / scale) * scale, p.y) * pre_scale;
            o[1] = (_Float16)q;
            q = copysignf(nvfp4_level(fabsf(p.z) / scale) * scale, p.z) * pre_scale;
            o[2] = (_Float16)q;
            q = copysignf(nvfp4_level(fabsf(p.w) / scale) * scale, p.w) * pre_scale;
            o[3] = (_Float16)q;
        }
        if (i < 4 || lane < 32) {
            _Float16* dst = xq + (size_t)t * H_DIM + fidx[i] * 4;
            *(uint2*)dst = *(const uint2*)o;
        }
    }
}

// ---------------- kernel 2: w fp32 -> fp16 ----------------
__global__ __launch_bounds__(256) void wconv_kernel(
    const float* __restrict__ w, _Float16* __restrict__ wq, int n)
{
    int i = (blockIdx.x * 256 + threadIdx.x) * 4;
    if (i < n) {
        float4 v = *(const float4*)(w + i);
        alignas(8) _Float16 o[4];
        o[0] = (_Float16)v.x;
        o[1] = (_Float16)v.y;
        o[2] = (_Float16)v.z;
        o[3] = (_Float16)v.w;
        *(uint2*)(wq + i) = *(const uint2*)o;
    }
}

// ---------------- async global->LDS 16B helper ----------------
__device__ __forceinline__ void async_copy16(const void* gptr, void* lptr)
{
    __builtin_amdgcn_global_load_lds(
        (const __attribute__((address_space(1))) unsigned int*)gptr,
        (__attribute__((address_space(3))) unsigned int*)lptr,
        16, 0, 0);
}

// ---------------- kernel 3: fp16 GEMM, C[t,o] = sum_k A[t,k]*B[o,k] + bias[o] ----
// 256x256 tile, BK=64, 512 threads (8 waves, 2Mx4N). Faithful m201-style schedule:
// 4 phases per K-tile, TWO barriers per phase, lgkmcnt(0) after the pre-barrier,
// half-tile staging units (16 KiB, 2 loads/thread) spread across phases with the
// retire chain "unit's last readers confirmed by the previous phase's post-barrier".
// Tile-boundary vmcnt(8)+barrier sits BEFORE the phase-3 MFMA cluster (hidden),
// and next-tile B/A0 ds_reads issue right after the phase-3 MFMAs (fly across the
// phase-3 post-barrier). Swizzle: linear LDS dest, inverse-swizzled global source,
// XOR-swizzled ds_read addresses.
#define BM 256
#define BN 256
#define BK 64

__global__ __launch_bounds__(512, 2) void gemm_bt_kernel(
    const _Float16* __restrict__ A,  // [M,K]
    const _Float16* __restrict__ B,  // [N,K]
    const float* __restrict__ bias,  // [N]
    float* __restrict__ C,           // [M,N]
    int M, int N, int K)
{
    __shared__ alignas(16) _Float16 sA[2][BM * BK];   // 64 KiB
    __shared__ alignas(16) _Float16 sB[2][BN * BK];   // 64 KiB

    const int tid    = threadIdx.x;
    const int wave   = tid >> 6;
    const int lane   = tid & 63;
    const int lane16 = lane & 15;
    const int quad   = lane >> 4;

    // XCD-aware block swizzle (nwg = 18*64 = 1152, divisible by 8 -> bijective)
    const int nbx = gridDim.x;
    const int nwg = nbx * gridDim.y;
    int bid = blockIdx.y * nbx + blockIdx.x;
    if ((nwg & 7) == 0) {
        const int cpx = nwg >> 3;
        bid = (bid & 7) * cpx + (bid >> 3);
    }
    const int m0 = (bid / nbx) * BM;
    const int n0 = (bid % nbx) * BN;

    const int wr = wave >> 2;   // 0..1 : 128-row half of M-tile (A-half consumed)
    const int wc = wave & 3;    // 0..3 : 64-col slice of N-tile (B-half = wc>>1)
    const int NT = K / BK;      // 18

    // Half-tile staging units: unit = 128 rows x 64 fp16 = 16 KiB = 1024 chunks of
    // 16 B; 512 threads x 2 loads. Chunk cu = (wave*2+s)*64 + lane (wave-uniform
    // base -> legal global_load_lds dest). row = h*128 + (cu>>3), slot = cu&7,
    // source slot XOR-swizzled so the linear LDS write equals the swizzled layout.
    int srcA[2][2], srcB[2][2], lofs[2][2];
    #pragma unroll
    for (int h = 0; h < 2; ++h)
        #pragma unroll
        for (int s = 0; s < 2; ++s) {
            const int cb = (wave * 2 + s) * 64;          // wave-uniform chunk base
            const int cu = cb + lane;
            const int rl = cu >> 3;                       // row within half, 0..127
            const int sw = ((cu & 7) * 8) ^ ((rl & 7) << 3);
            srcA[h][s] = (m0 + h * 128 + rl) * K + sw;
            srcB[h][s] = (n0 + h * 128 + rl) * K + sw;
            lofs[h][s] = (h * 1024 + cb) * 16;            // byte offset in buffer
        }

    auto stageA = [&](int tt, int dd, int h) {
        const int k0 = tt * BK;
        #pragma unroll
        for (int s = 0; s < 2; ++s)
            async_copy16(A + srcA[h][s] + k0, (char*)(&sA[dd][0]) + lofs[h][s]);
    };
    auto stageB = [&](int tt, int dd, int h) {
        const int k0 = tt * BK;
        #pragma unroll
        for (int s = 0; s < 2; ++s)
            async_copy16(B + srcB[h][s] + k0, (char*)(&sB[dd][0]) + lofs[h][s]);
    };

    // ds_read XOR term: fragment row & 7 == lane16 & 7 -> per-thread constant
    const int xr = (lane16 & 7) << 3;

    f16x8 aR0[2][2], aR1[2][2];   // named double-buffer (all static indexing)
    f16x8 b[4][2];
    f32x4 acc[8][4] = {};

    auto readA0 = [&](const _Float16* tA, int qd) {
        #pragma unroll
        for (int ii = 0; ii < 2; ++ii) {
            const int r = wr * 128 + (qd * 2 + ii) * 16 + lane16;
            #pragma unroll
            for (int ks = 0; ks < 2; ++ks)
                aR0[ii][ks] = *(const f16x8*)(tA + r * 64 + ((ks * 32 + quad * 8) ^ xr));
        }
    };
    auto readA1 = [&](const _Float16* tA, int qd) {
        #pragma unroll
        for (int ii = 0; ii < 2; ++ii) {
            const int r = wr * 128 + (qd * 2 + ii) * 16 + lane16;
            #pragma unroll
            for (int ks = 0; ks < 2; ++ks)
                aR1[ii][ks] = *(const f16x8*)(tA + r * 64 + ((ks * 32 + quad * 8) ^ xr));
        }
    };
    auto readB = [&](const _Float16* tB) {
        #pragma unroll
        for (int j = 0; j < 4; ++j) {
            const int rb = wc * 64 + j * 16 + lane16;
            #pragma unroll
            for (int ks = 0; ks < 2; ++ks)
                b[j][ks] = *(const f16x8*)(tB + rb * 64 + ((ks * 32 + quad * 8) ^ xr));
        }
    };

#define MFMA_Q(q, AR) do {                                                        \
    __builtin_amdgcn_s_setprio(1);                                                \
    _Pragma("unroll")                                                             \
    for (int ii = 0; ii < 2; ++ii)                                                \
        _Pragma("unroll")                                                         \
        for (int j = 0; j < 4; ++j)                                               \
            _Pragma("unroll")                                                     \
            for (int ks = 0; ks < 2; ++ks)                                        \
                acc[(q) * 2 + ii][j] = __builtin_amdgcn_mfma_f32_16x16x32_f16(    \
                    AR[ii][ks], b[j][ks], acc[(q) * 2 + ii][j], 0, 0, 0);         \
    __builtin_amdgcn_s_setprio(0);                                                \
} while (0)

    // prologue: tiles 0 and 1 fully staged; wait tile 0 (oldest 8), then first reads
    stageB(0, 0, 0); stageB(0, 0, 1); stageA(0, 0, 0); stageA(0, 0, 1);
    stageB(1, 1, 0); stageB(1, 1, 1); stageA(1, 1, 0); stageA(1, 1, 1);
    asm volatile("s_waitcnt vmcnt(8)" ::: "memory");
    __builtin_amdgcn_s_barrier();
    asm volatile("" ::: "memory");
    readB(&sB[0][0]);
    readA0(&sA[0][0], 0);

    for (int t = 0; t < NT; ++t) {
        const int d = t & 1;
        const _Float16* tA = &sA[d][0];
        const bool pf = (t + 2 < NT);

        // ---- phase 0: MFMA q0 (aR0 from prev phase-3/prologue) ----
        readA1(tA, 1);
        __builtin_amdgcn_s_barrier();
        asm volatile("s_waitcnt lgkmcnt(0)" ::: "memory");
        MFMA_Q(0, aR0);
        __builtin_amdgcn_s_barrier();
        // post-barrier: all waves' B(t) + A-q0(t) reads confirmed -> B half0 of
        // buffer d is retireable.

        // ---- phase 1: MFMA q1 ----
        readA0(tA, 2);
        if (pf) stageB(t + 2, d, 0);          // overwrites retired B-half0
        __builtin_amdgcn_s_barrier();
        asm volatile("s_waitcnt lgkmcnt(0)" ::: "memory");
        MFMA_Q(1, aR1);
        __builtin_amdgcn_s_barrier();

        // ---- phase 2: MFMA q2 ----
        readA1(tA, 3);
        if (pf) stageB(t + 2, d, 1);          // B-half1 retired since phase 0
        __builtin_amdgcn_s_barrier();
        asm volatile("s_waitcnt lgkmcnt(0)" ::: "memory");
        MFMA_Q(2, aR0);
        __builtin_amdgcn_s_barrier();
        // post-barrier: all waves' A(t) reads (last issued phase 2) confirmed ->
        // A halves of buffer d retireable.

        // ---- phase 3: tile boundary + MFMA q3 ----
        if (pf) { stageA(t + 2, d, 0); stageA(t + 2, d, 1); }
        if (pf) asm volatile("s_waitcnt vmcnt(8)" ::: "memory");  // t+1 landed
        else    asm volatile("s_waitcnt vmcnt(0)" ::: "memory");
        __builtin_amdgcn_s_barrier();          // publish: every wave's t+1 landed
        asm volatile("" ::: "memory");
        MFMA_Q(3, aR1);
        if (t + 1 < NT) {
            // next tile's B + A-q0 reads issue behind the q3 MFMA burst and fly
            // across the post-barrier; drained by phase-0's lgkmcnt(0).
            readB(&sB[d ^ 1][0]);
            readA0(&sA[d ^ 1][0], 0);
        }
        __builtin_amdgcn_s_barrier();
    }

    // epilogue: C/D layout col = lane16, row = quad*4 + reg
    #pragma unroll
    for (int i = 0; i < 8; ++i) {
        const int m = m0 + wr * 128 + i * 16 + quad * 4;
        #pragma unroll
        for (int j = 0; j < 4; ++j) {
            const int n = n0 + wc * 64 + j * 16 + lane16;
            const float bv = bias[n];
            float* cp = C + (size_t)m * N + n;
            #pragma unroll
            for (int r2 = 0; r2 < 4; ++r2)
                cp[(size_t)r2 * N] = acc[i][j][r2] + bv;
        }
    }
#undef MFMA_Q
}

// ---------------- launch ----------------
extern "C" void kernel_launch(void* const* d_in, const int* in_sizes, int n_in,
                              void* d_out, int out_size, void* d_ws, size_t ws_size,
                              hipStream_t stream)
{
    const float* x      = (const float*)d_in[0];
    const float* w      = (const float*)d_in[1];
    const float* smooth = (const float*)d_in[2];
    const float* bias   = (const float*)d_in[3];
    float* out = (float*)d_out;

    const int H = in_sizes[2];            // 1152
    const int T = in_sizes[0] / H;        // 16384
    const int O = in_sizes[3];            // 4608

    _Float16* xq = (_Float16*)d_ws;
    _Float16* wq = (_Float16*)((char*)d_ws + (size_t)T * H * sizeof(_Float16));

    quant_kernel<<<T / 4, 256, 0, stream>>>((const float4*)x, (const float4*)smooth, xq);
    wconv_kernel<<<(O * H / 4 + 255) / 256, 256, 0, stream>>>(w, wq, O * H);

    dim3 grid(O / BN, T / BM);
    gemm_bt_kernel<<<grid, 512, 0, stream>>>(xq, wq, bias, out, T, O, H);
}